// Round 1
// baseline (973.175 us; speedup 1.0000x reference)
//
#include <hip/hip_runtime.h>

// Problem constants (fixed by setup_inputs)
constexpr int B = 8;
constexpr int N = 50000;
constexpr int T = 64;          // temporal length, contiguous innermost (last dim is 1)
constexpr int E = 1600000;
constexpr int HIDDEN = 256;
constexpr int HOR = 24;
#define EPS 0.001f

// ---------------------------------------------------------------------------
// 1) degree pass: weighted out-degree (for iso) and in-degree count (for GCN norm)
__global__ void deg_kernel(const int* __restrict__ ei, const float* __restrict__ ew,
                           float* __restrict__ deg_w, int* __restrict__ degc) {
    int e = blockIdx.x * blockDim.x + threadIdx.x;
    if (e >= E) return;
    int s = ei[e];       // edge_index[0][e] (src)
    int d = ei[E + e];   // edge_index[1][e] (dst)
    atomicAdd(&deg_w[s], ew[e]);
    atomicAdd(&degc[d], 1);
}

// 2) prep: iso = 1/(deg_w+eps); dinv = rsqrt(in_deg + 1)  (self-loop adds 1, so deg>0 always)
__global__ void prep_kernel(const float* __restrict__ deg_w, const int* __restrict__ degc,
                            float* __restrict__ iso, float* __restrict__ dinv) {
    int n = blockIdx.x * blockDim.x + threadIdx.x;
    if (n >= N) return;
    iso[n]  = 1.0f / (deg_w[n] + EPS);
    dinv[n] = rsqrtf((float)(degc[n] + 1));
}

// 3) temporal mean * iso. 16 lanes per (b,n) pair, float4 loads → each wave reads 1KB contiguous.
__global__ void xmean_kernel(const float* __restrict__ x, const float* __restrict__ iso,
                             float* __restrict__ xw) {
    int tid = blockIdx.x * blockDim.x + threadIdx.x;
    int p = tid >> 4;          // (b,n) pair index
    int l = tid & 15;
    if (p >= B * N) return;
    float4 v = ((const float4*)x)[(size_t)p * 16 + l];   // 64 floats per pair
    float sum = v.x + v.y + v.z + v.w;
    // reduce across the 16-lane group (within one 64-lane wave)
    sum += __shfl_xor(sum, 1);
    sum += __shfl_xor(sum, 2);
    sum += __shfl_xor(sum, 4);
    sum += __shfl_xor(sum, 8);
    if (l == 0) {
        int n = p % N;
        xw[p] = (sum * (1.0f / 64.0f)) * iso[n];
    }
}

// 4) rank-1 head collapse: W[k] = gcn_weight . proj_weight[:,k]; C[k] = gcn_bias . proj_weight[:,k] + proj_bias[k]
__global__ void wc_kernel(const float* __restrict__ gw, const float* __restrict__ gb,
                          const float* __restrict__ pw, const float* __restrict__ pb,
                          float* __restrict__ wc) {
    int k = threadIdx.x;
    if (k >= HOR) return;
    float w = 0.0f, c = 0.0f;
    for (int h = 0; h < HIDDEN; ++h) {
        float p = pw[h * HOR + k];
        w += gw[h] * p;
        c += gb[h] * p;
    }
    wc[k] = w;
    wc[HOR + k] = c + pb[k];
}

// 5) edge scatter: sacc[b,dst] += xw[b,src] * dinv[src] * dinv[dst]
__global__ void scatter_kernel(const int* __restrict__ ei, const float* __restrict__ dinv,
                               const float* __restrict__ xw, float* __restrict__ sacc) {
    int e = blockIdx.x * blockDim.x + threadIdx.x;
    if (e >= E) return;
    int s = ei[e];
    int d = ei[E + e];
    float nrm = dinv[s] * dinv[d];
#pragma unroll
    for (int b = 0; b < B; ++b) {
        atomicAdd(&sacc[b * N + d], xw[b * N + s] * nrm);
    }
}

// 6) output: out[b,n,k] = (sacc[b,n] + xw[b,n]*dinv[n]^2) * W[k] + C[k], coalesced writes
__global__ void out_kernel(const float* __restrict__ sacc, const float* __restrict__ xw,
                           const float* __restrict__ dinv, const float* __restrict__ wc,
                           float* __restrict__ out) {
    int idx = blockIdx.x * blockDim.x + threadIdx.x;
    if (idx >= B * N * HOR) return;
    int p = idx / HOR;
    int k = idx - p * HOR;
    int n = p % N;
    float dv = dinv[n];
    float agg = sacc[p] + xw[p] * dv * dv;
    out[idx] = agg * wc[k] + wc[HOR + k];
}

extern "C" void kernel_launch(void* const* d_in, const int* in_sizes, int n_in,
                              void* d_out, int out_size, void* d_ws, size_t ws_size,
                              hipStream_t stream) {
    const float* x  = (const float*)d_in[0];   // [B,N,T,1] f32
    const int*   ei = (const int*)d_in[1];     // [2,E] i32
    const float* ew = (const float*)d_in[2];   // [E] f32
    const float* gw = (const float*)d_in[3];   // [256] f32
    const float* gb = (const float*)d_in[4];   // [256] f32
    const float* pw = (const float*)d_in[5];   // [256,24] f32
    const float* pb = (const float*)d_in[6];   // [24] f32
    float* out = (float*)d_out;

    char* ws = (char*)d_ws;
    // layout: [deg_w N][degc N][sacc B*N]  <- zeroed together
    //         [iso N][dinv N][xw B*N][wc 48]
    float* deg_w = (float*)ws;
    int*   degc  = (int*)(ws + (size_t)N * 4);
    float* sacc  = (float*)(ws + (size_t)2 * N * 4);
    float* iso   = (float*)(ws + (size_t)(2 + B) * N * 4);
    float* dinv  = (float*)(ws + (size_t)(3 + B) * N * 4);
    float* xw    = (float*)(ws + (size_t)(4 + B) * N * 4);
    float* wc    = (float*)(ws + (size_t)(4 + 2 * B) * N * 4);

    // zero accumulators (deg_w, degc, sacc) — ws is poisoned 0xAA before every call
    hipMemsetAsync(ws, 0, (size_t)(2 + B) * N * 4, stream);

    deg_kernel<<<(E + 255) / 256, 256, 0, stream>>>(ei, ew, deg_w, degc);
    prep_kernel<<<(N + 255) / 256, 256, 0, stream>>>(deg_w, degc, iso, dinv);
    xmean_kernel<<<(B * N * 16 + 255) / 256, 256, 0, stream>>>(x, iso, xw);
    wc_kernel<<<1, 32, 0, stream>>>(gw, gb, pw, pb, wc);
    scatter_kernel<<<(E + 255) / 256, 256, 0, stream>>>(ei, dinv, xw, sacc);
    out_kernel<<<(B * N * HOR + 255) / 256, 256, 0, stream>>>(sacc, xw, dinv, wc, out);
}